// Round 21
// baseline (233.527 us; speedup 1.0000x reference)
//
#include <hip/hip_runtime.h>
#include <stdint.h>

typedef unsigned int u32;
typedef unsigned short u16;
typedef unsigned long long u64;
typedef __attribute__((ext_vector_type(8))) short bf16x8;
typedef __attribute__((ext_vector_type(4))) float f32x4;

#define HC 32

__device__ __forceinline__ float u2f(u32 u){ union{u32 i;float f;}v; v.i=u; return v.f; }
__device__ __forceinline__ u16 f2bf(float f){ union{float f;u32 i;}v; v.f=f; u32 i=v.i;
    return (u16)((i + 0x7FFFu + ((i>>16)&1u))>>16); }  // RNE
__device__ __forceinline__ short bfs(float f){ return (short)f2bf(f); }
__device__ __forceinline__ u32 packbf(float a, float b){ return (u32)f2bf(a) | ((u32)f2bf(b)<<16); }

// ---- K0: B-fragments for 4 conv matrices (slot = mat*54 + k*2 + oh) ----
__global__ __launch_bounds__(256) void k0_prep(
    const float* __restrict__ Wq1, const float* __restrict__ Wq2,
    const float* __restrict__ Wr1, const float* __restrict__ Wr2,
    u16* __restrict__ wsB)
{
    int it = blockIdx.x*256 + threadIdx.x;
    if (it >= 216*64) return;
    int l = it & 63, slot = it >> 6;
    int oh = slot & 1, k = (slot >> 1) % 27, mat = slot / 54;
    const float* W = (mat==0)?Wq1:(mat==1)?Wq2:(mat==2)?Wr1:Wr2;
    const float* src = W + k*1024 + oh*16 + (l & 15);
    int crow = (l >> 4) * 8;
    u32 w4[4];
    #pragma unroll
    for (int jj = 0; jj < 4; ++jj)
        w4[jj] = packbf(src[(crow + 2*jj)*32], src[(crow + 2*jj + 1)*32]);
    *(uint4*)&wsB[slot*512 + l*8] = make_uint4(w4[0], w4[1], w4[2], w4[3]);
}

// ---- K1: y = x @ Wg1 + bg1 -> cv | gl  (MFMA) ----
__global__ __launch_bounds__(256) void k1_mfma(
    const float* __restrict__ x, const float* __restrict__ Wg1, const float* __restrict__ bg1,
    float* __restrict__ cv, float* __restrict__ gl, long long N)
{
    const int lane = threadIdx.x & 63;
    const int m = lane & 15, g = lane >> 4;
    bf16x8 bw[4][2];
    #pragma unroll
    for (int no = 0; no < 4; ++no)
      #pragma unroll
      for (int kf = 0; kf < 2; ++kf)
        #pragma unroll
        for (int j = 0; j < 8; ++j)
            bw[no][kf][j] = bfs(Wg1[(kf*32 + g*8 + j)*64 + no*16 + m]);
    float bias4[4];
    #pragma unroll
    for (int no = 0; no < 4; ++no) bias4[no] = bg1[no*16 + m];

    const long long wave = (long long)blockIdx.x*4 + (threadIdx.x>>6);
    long long t0 = wave * 4;
    #pragma unroll 1
    for (long long t = t0; t < t0+4; ++t) {
        long long p0 = t*16;
        if (p0 >= N) break;
        long long pr_a = p0 + m; if (pr_a > N-1) pr_a = N-1;
        const float4* xr = (const float4*)(x + pr_a*64);
        bf16x8 aw[2];
        #pragma unroll
        for (int kf = 0; kf < 2; ++kf) {
            float4 lo = xr[kf*8 + g*2];
            float4 hi = xr[kf*8 + g*2 + 1];
            aw[kf][0]=bfs(lo.x); aw[kf][1]=bfs(lo.y); aw[kf][2]=bfs(lo.z); aw[kf][3]=bfs(lo.w);
            aw[kf][4]=bfs(hi.x); aw[kf][5]=bfs(hi.y); aw[kf][6]=bfs(hi.z); aw[kf][7]=bfs(hi.w);
        }
        #pragma unroll
        for (int no = 0; no < 4; ++no) {
            f32x4 acc = {0.f,0.f,0.f,0.f};
            acc = __builtin_amdgcn_mfma_f32_16x16x32_bf16(aw[0], bw[no][0], acc, 0,0,0);
            acc = __builtin_amdgcn_mfma_f32_16x16x32_bf16(aw[1], bw[no][1], acc, 0,0,0);
            #pragma unroll
            for (int j = 0; j < 4; ++j) {
                long long pr = p0 + g*4 + j;
                if (pr < N) {
                    float v = acc[j] + bias4[no];
                    if (no < 2) cv[pr*32 + no*16 + m] = v;
                    else        gl[pr*32 + (no-2)*16 + m] = v;
                }
            }
        }
    }
}

// ---- tile machinery ----
__device__ __forceinline__ void load_nbr(
    const int* __restrict__ nbr, long long N, long long p0, int lane, int* nbrv)
{
    #pragma unroll
    for (int ch = 0; ch < 7; ++ch) {
        int i = ch*64 + lane;
        int kk = i >> 4, pp = i & 15;
        nbrv[ch] = (i < 432 && p0 + pp < N) ? nbr[(long long)kk*N + p0 + pp] : -1;
    }
}

__device__ __forceinline__ void enum_tile_reg(
    const int* nbrv,
    u16* plist, int* ilist, u16* slist, u16* sstart,
    int lane, u32& np_out, u32& ns_out)
{
    u32 np = 0, ns = 0;
    #pragma unroll
    for (int ch = 0; ch < 7; ++ch) {
        int i = ch*64 + lane;
        int kk = i >> 4, pp = i & 15;
        int ixv = nbrv[ch];
        u64 b = __ballot(ixv >= 0);
        u32 kact = 0;
        #pragma unroll
        for (int q2 = 0; q2 < 4; ++q2)
            kact |= ((((b >> (16*q2)) & 0xffffull) != 0ull) ? 1u : 0u) << q2;
        if (ixv >= 0) {
            u64 ltm = (1ull << lane) - 1ull;
            u32 pos = np + (u32)__popcll(b & ltm);
            int q2 = lane >> 4;
            u32 s = ns + __popc(kact & ((1u << q2) - 1u));
            if (pos < 224) {
                plist[pos] = (u16)((s << 9) | (u32)pp);
                ilist[pos] = ixv;
                u64 subm = 0xffffull << (16*q2);
                if ((b & subm & ltm) == 0ull) { slist[s] = (u16)kk; sstart[s] = (u16)pos; }
            }
        }
        np += (u32)__popcll(b);
        ns += __popc(kact);
    }
    if (np > 224) np = 224;
    np_out = np; ns_out = ns;
}

template<int KAv>
__device__ __forceinline__ void gather_batch(
    const float* __restrict__ src, u16* A,
    const u16* plist, const int* ilist,
    u32 jS, u32 jE, u32 base, int c32, int hf)
{
    constexpr int STR = KAv*32 + 8;
    constexpr int U4R = KAv*4;
    constexpr int NU4 = 16*U4R;
    const int lane = threadIdx.x & 63;
    uint4 z4 = make_uint4(0u,0u,0u,0u);
    #pragma unroll
    for (int w = 0; w < NU4/64; ++w) {
        int q = w*64 + lane;
        int r = q / U4R, c8 = q - r*U4R;
        *(uint4*)&A[r*STR + c8*8] = z4;
    }
    asm volatile("s_waitcnt lgkmcnt(0)" ::: "memory");
    for (u32 j0 = jS; j0 < jE; j0 += 16) {
        float v[8]; u32 mt[8];
        #pragma unroll
        for (int tt = 0; tt < 8; ++tt) {
            u32 pj = j0 + 2*tt + (u32)hf;
            bool val = pj < jE;
            u32 pm = val ? (u32)plist[pj] : 0u;
            int ix = val ? ilist[pj] : 0;
            mt[tt] = val ? (pm | 0x80000000u) : 0u;
            v[tt] = val ? src[(long long)ix*32 + c32] : 0.f;
        }
        #pragma unroll
        for (int tt = 0; tt < 8; ++tt) {
            if (mt[tt] >> 31) {
                u32 sl = ((mt[tt] >> 9) & 31u) - base;
                u32 p = mt[tt] & 15u;
                A[p*STR + sl*32 + c32] = f2bf(v[tt]);
            }
        }
    }
    asm volatile("s_waitcnt lgkmcnt(0)" ::: "memory");
}

// ---- K2: wave-specialized MFMA-tile conv (waves 0-1: r-path on cv; waves 2-3: q-path on gl) ----
#define KA2 5
#define STR2 (KA2*32 + 8)
__global__ __launch_bounds__(256, 1) void k2_mfma(
    const float* __restrict__ cv, const float* __restrict__ gl,
    const int* __restrict__ nbr, const int* __restrict__ batch_id,
    const u16* __restrict__ wsB,
    const float* __restrict__ br1, const float* __restrict__ bq1,
    const float* __restrict__ bq2,
    float* __restrict__ r1, float* __restrict__ s12, float* __restrict__ m1,
    float* __restrict__ bsum, long long N)
{
    __shared__ __align__(16) u16 Abuf[4][16*STR2];
    __shared__ u16 plist_s[4][224];
    __shared__ int ilist_s[4][224];
    __shared__ u16 slist_s[4][32];
    __shared__ u16 sstart_s[4][32];
    __shared__ float lbs[128];

    if (threadIdx.x < 128) lbs[threadIdx.x] = 0.f;
    __syncthreads();

    const int wid = threadIdx.x >> 6;
    const int lane = threadIdx.x & 63;
    const int m = lane & 15, g = lane >> 4;
    const int c32 = lane & 31, hf = lane >> 5;
    u16* A = Abuf[wid];
    u16* plist = plist_s[wid];
    int* ilist = ilist_s[wid];
    u16* slist = slist_s[wid];
    u16* sstart = sstart_s[wid];

    const long long ntiles = (N + 15) >> 4;
    const long long tstride = (long long)gridDim.x*2;

    if (wid < 2) {
        // ---- r-path: r1 = relu(sconv(cv, Wr1) + br1) ----
        const float bra = br1[m], brb = br1[16+m];
        long long t = (long long)blockIdx.x*2 + wid;
        int nbrv[7];
        if (t < ntiles) load_nbr(nbr, N, t*16, lane, nbrv);
        for (; t < ntiles; ) {
            const long long p0 = t*16;
            u32 np, ns;
            enum_tile_reg(nbrv, plist, ilist, slist, sstart, lane, np, ns);
            long long tn = t + tstride;
            if (tn < ntiles) load_nbr(nbr, N, tn*16, lane, nbrv);

            f32x4 accr0 = {0.f,0.f,0.f,0.f}, accr1 = {0.f,0.f,0.f,0.f};
            asm volatile("s_waitcnt lgkmcnt(0)" ::: "memory");
            for (u32 base = 0; base < ns; base += KA2) {
                u32 sEnd = base + KA2; if (sEnd > ns) sEnd = ns;
                u32 jS = sstart[base];
                u32 jE = (sEnd < ns) ? (u32)sstart[sEnd] : np;
                gather_batch<KA2>(cv, A, plist, ilist, jS, jE, base, c32, hf);
                for (u32 s = base; s < sEnd; ++s) {
                    int sl = (int)(s - base);
                    int k = slist[s];
                    bf16x8 af  = *(const bf16x8*)&A[m*STR2 + sl*32 + g*8];
                    bf16x8 wr0 = *(const bf16x8*)&wsB[(108 + k*2 + 0)*512 + lane*8];
                    bf16x8 wr1v = *(const bf16x8*)&wsB[(108 + k*2 + 1)*512 + lane*8];
                    accr0 = __builtin_amdgcn_mfma_f32_16x16x32_bf16(af, wr0, accr0, 0,0,0);
                    accr1 = __builtin_amdgcn_mfma_f32_16x16x32_bf16(af, wr1v, accr1, 0,0,0);
                }
            }
            #pragma unroll
            for (int j = 0; j < 4; ++j) {
                long long pr = p0 + g*4 + j;
                if (pr < N) {
                    r1[pr*32 + m]      = fmaxf(accr0[j] + bra, 0.f);
                    r1[pr*32 + 16 + m] = fmaxf(accr1[j] + brb, 0.f);
                }
            }
            t = tn;
        }
    } else {
        // ---- q-path: out1/out2 convs on gl -> s12, m1, bsum ----
        const float b1a = bq1[m], b1b = bq1[16+m], b2a = bq2[m], b2b = bq2[16+m];
        long long t = (long long)blockIdx.x*2 + (wid - 2);
        int nbrv[7];
        if (t < ntiles) load_nbr(nbr, N, t*16, lane, nbrv);
        for (; t < ntiles; ) {
            const long long p0 = t*16;
            u32 np, ns;
            enum_tile_reg(nbrv, plist, ilist, slist, sstart, lane, np, ns);
            long long tn = t + tstride;
            if (tn < ntiles) load_nbr(nbr, N, tn*16, lane, nbrv);
            int bb[4];
            #pragma unroll
            for (int j = 0; j < 4; ++j) {
                long long pr = p0 + g*4 + j; if (pr > N-1) pr = N-1;
                bb[j] = batch_id[pr];
            }

            f32x4 acc10 = {0.f,0.f,0.f,0.f}, acc11 = {0.f,0.f,0.f,0.f};
            f32x4 acc20 = {0.f,0.f,0.f,0.f}, acc21 = {0.f,0.f,0.f,0.f};
            asm volatile("s_waitcnt lgkmcnt(0)" ::: "memory");
            for (u32 base = 0; base < ns; base += KA2) {
                u32 sEnd = base + KA2; if (sEnd > ns) sEnd = ns;
                u32 jS = sstart[base];
                u32 jE = (sEnd < ns) ? (u32)sstart[sEnd] : np;
                gather_batch<KA2>(gl, A, plist, ilist, jS, jE, base, c32, hf);
                for (u32 s = base; s < sEnd; ++s) {
                    int sl = (int)(s - base);
                    int k = slist[s];
                    bf16x8 af  = *(const bf16x8*)&A[m*STR2 + sl*32 + g*8];
                    bf16x8 w10 = *(const bf16x8*)&wsB[(k*2 + 0)*512 + lane*8];
                    bf16x8 w11 = *(const bf16x8*)&wsB[(k*2 + 1)*512 + lane*8];
                    bf16x8 w20 = *(const bf16x8*)&wsB[(54 + k*2 + 0)*512 + lane*8];
                    bf16x8 w21 = *(const bf16x8*)&wsB[(54 + k*2 + 1)*512 + lane*8];
                    acc10 = __builtin_amdgcn_mfma_f32_16x16x32_bf16(af, w10, acc10, 0,0,0);
                    acc11 = __builtin_amdgcn_mfma_f32_16x16x32_bf16(af, w11, acc11, 0,0,0);
                    acc20 = __builtin_amdgcn_mfma_f32_16x16x32_bf16(af, w20, acc20, 0,0,0);
                    acc21 = __builtin_amdgcn_mfma_f32_16x16x32_bf16(af, w21, acc21, 0,0,0);
                }
            }
            #pragma unroll
            for (int j = 0; j < 4; ++j) {
                long long pr = p0 + g*4 + j;
                if (pr < N) {
                    float o1a = fmaxf(acc10[j] + b1a, 0.f);
                    float o1b = fmaxf(acc11[j] + b1b, 0.f);
                    float o2a = fmaxf(acc20[j] + b2a, 0.f);
                    float o2b = fmaxf(acc21[j] + b2b, 0.f);
                    s12[pr*32 + m]      = o1a + o2a;
                    s12[pr*32 + 16 + m] = o1b + o2b;
                    float rs = o1a + o1b;
                    #pragma unroll
                    for (int d = 1; d < 16; d <<= 1) rs += __shfl_xor(rs, d, 64);
                    if (m == 0) m1[pr] = rs * (1.f/32.f);
                    atomicAdd(&lbs[bb[j]*32 + m], o2a);
                    atomicAdd(&lbs[bb[j]*32 + 16 + m], o2b);
                }
            }
            t = tn;
        }
    }
    __syncthreads();
    if (threadIdx.x < 128) atomicAdd(&bsum[threadIdx.x], lbs[threadIdx.x]);
}

// ---- K3: r2-conv (KA=10) + epilogue prefetch + nbr pipeline -> out (round-17 proven) ----
#define KA3 10
#define STR3 (KA3*32 + 8)
__global__ __launch_bounds__(256, 1) void k3_mfma(
    const float* __restrict__ r1, const float* __restrict__ cv,
    const float* __restrict__ gl, const float* __restrict__ s12,
    const float* __restrict__ m1, const float* __restrict__ bsum,
    const int* __restrict__ nbr, const int* __restrict__ batch_id,
    const u16* __restrict__ wsB, const float* __restrict__ br2,
    const float* __restrict__ Wq3, const float* __restrict__ bq3,
    const float* __restrict__ Wg2, const float* __restrict__ bg2,
    const float* __restrict__ x, float* __restrict__ out,
    long long N, const int* __restrict__ bsz)
{
    __shared__ __align__(16) u16 Acmp[4][16*STR3];
    __shared__ u16 plist_s[4][224];
    __shared__ int ilist_s[4][224];
    __shared__ u16 slist_s[4][32];
    __shared__ u16 sstart_s[4][32];

    const int wid = threadIdx.x >> 6;
    const int lane = threadIdx.x & 63;
    const int m = lane & 15, g = lane >> 4;
    const int c32 = lane & 31, hf = lane >> 5;
    u16* A = Acmp[wid];
    u16* plist = plist_s[wid];
    int* ilist = ilist_s[wid];
    u16* slist = slist_s[wid];
    u16* sstart = sstart_s[wid];
    u16* fin_bf = A;          // aliased into A (dead after conv)
    u16* a2_bf  = A + 640;

    bf16x8 bq[2];
    #pragma unroll
    for (int no = 0; no < 2; ++no)
      #pragma unroll
      for (int j = 0; j < 8; ++j)
        bq[no][j] = bfs(Wq3[(g*8+j)*32 + no*16 + m]);
    bf16x8 bgw[4][2];
    #pragma unroll
    for (int no = 0; no < 4; ++no)
      #pragma unroll
      for (int kf = 0; kf < 2; ++kf)
        #pragma unroll
        for (int j = 0; j < 8; ++j)
          bgw[no][kf][j] = bfs(Wg2[(kf*32 + g*8 + j)*64 + no*16 + m]);
    const float br2a = br2[m], br2b = br2[16+m];
    const float bq3a = bq3[m], bq3b = bq3[16+m];
    float bgb[4];
    #pragma unroll
    for (int no = 0; no < 4; ++no) bgb[no] = bg2[no*16 + m];
    const float invNP = (float)(*bsz) / (float)N;
    const int p_lin = lane >> 2, c0 = (lane & 3) * 8;

    const long long ntiles = (N + 15) >> 4;
    const long long tstride = (long long)gridDim.x*4;
    long long t = (long long)blockIdx.x*4 + wid;
    int nbrv[7];
    if (t < ntiles) load_nbr(nbr, N, t*16, lane, nbrv);
    for (; t < ntiles; ) {
        const long long p0 = t*16;
        u32 np, ns;
        enum_tile_reg(nbrv, plist, ilist, slist, sstart, lane, np, ns);
        long long tn = t + tstride;
        if (tn < ntiles) load_nbr(nbr, N, tn*16, lane, nbrv);

        // ---- PREFETCH epilogue operands ----
        float cva[4], cvb[4], gla[4], glb[4], xv[4][4];
        #pragma unroll
        for (int j = 0; j < 4; ++j) {
            int row = g*4 + j;
            long long pr = p0 + row; if (pr > N-1) pr = N-1;
            cva[j] = cv[pr*32 + m];      cvb[j] = cv[pr*32 + 16 + m];
            gla[j] = gl[pr*32 + m];      glb[j] = gl[pr*32 + 16 + m];
            #pragma unroll
            for (int no = 0; no < 4; ++no) xv[no][j] = x[pr*64 + no*16 + m];
        }
        float m1v; float bsv[8], sv[8];
        {
            long long pp = p0 + p_lin; if (pp > N-1) pp = N-1;
            m1v = m1[pp];
            int b = batch_id[pp];
            const float4* bsp = (const float4*)(bsum + b*32 + c0);
            float4 bs0 = bsp[0], bs1 = bsp[1];
            const float4* s12p = (const float4*)(s12 + pp*32 + c0);
            float4 s0 = s12p[0], s1 = s12p[1];
            bsv[0]=bs0.x; bsv[1]=bs0.y; bsv[2]=bs0.z; bsv[3]=bs0.w;
            bsv[4]=bs1.x; bsv[5]=bs1.y; bsv[6]=bs1.z; bsv[7]=bs1.w;
            sv[0]=s0.x; sv[1]=s0.y; sv[2]=s0.z; sv[3]=s0.w;
            sv[4]=s1.x; sv[5]=s1.y; sv[6]=s1.z; sv[7]=s1.w;
        }

        // ---- conv phase ----
        f32x4 acc0 = {0.f,0.f,0.f,0.f}, acc1 = {0.f,0.f,0.f,0.f};
        asm volatile("s_waitcnt lgkmcnt(0)" ::: "memory");
        for (u32 base = 0; base < ns; base += KA3) {
            u32 sEnd = base + KA3; if (sEnd > ns) sEnd = ns;
            u32 jS = sstart[base];
            u32 jE = (sEnd < ns) ? (u32)sstart[sEnd] : np;
            gather_batch<KA3>(r1, A, plist, ilist, jS, jE, base, c32, hf);
            for (u32 s = base; s < sEnd; ++s) {
                int sl = (int)(s - base);
                int k = slist[s];
                bf16x8 af = *(const bf16x8*)&A[m*STR3 + sl*32 + g*8];
                bf16x8 w0 = *(const bf16x8*)&wsB[(162 + k*2 + 0)*512 + lane*8];
                bf16x8 w1 = *(const bf16x8*)&wsB[(162 + k*2 + 1)*512 + lane*8];
                acc0 = __builtin_amdgcn_mfma_f32_16x16x32_bf16(af, w0, acc0, 0,0,0);
                acc1 = __builtin_amdgcn_mfma_f32_16x16x32_bf16(af, w1, acc1, 0,0,0);
            }
        }
        asm volatile("s_waitcnt lgkmcnt(0)" ::: "memory");
        // cx2 -> a2 tile
        #pragma unroll
        for (int j = 0; j < 4; ++j) {
            int row = g*4 + j;
            a2_bf[row*72 + m]      = f2bf(fmaxf(acc0[j] + br2a, 0.f) + 2.f*cva[j]);
            a2_bf[row*72 + 16 + m] = f2bf(fmaxf(acc1[j] + br2b, 0.f) + 2.f*cvb[j]);
        }
        {
            bf16x8 fbv;
            #pragma unroll
            for (int j = 0; j < 8; ++j) {
                float enc = sqrtf(m1v * bsv[j] * invNP + 1e-12f);
                fbv[j] = bfs(enc + sv[j]);
            }
            *(bf16x8*)&fin_bf[p_lin*40 + c0] = fbv;
        }
        asm volatile("s_waitcnt lgkmcnt(0)" ::: "memory");
        bf16x8 af2 = *(const bf16x8*)&fin_bf[m*40 + g*8];
        f32x4 f0 = {0.f,0.f,0.f,0.f}, f1 = {0.f,0.f,0.f,0.f};
        f0 = __builtin_amdgcn_mfma_f32_16x16x32_bf16(af2, bq[0], f0, 0,0,0);
        f1 = __builtin_amdgcn_mfma_f32_16x16x32_bf16(af2, bq[1], f1, 0,0,0);
        #pragma unroll
        for (int j = 0; j < 4; ++j) {
            int row = g*4 + j;
            float fa = fmaxf(f0[j] + bq3a, 0.f);
            float fb = fmaxf(f1[j] + bq3b, 0.f);
            a2_bf[row*72 + 32 + m] = f2bf(fmaxf(gla[j] - fa, 0.f));
            a2_bf[row*72 + 48 + m] = f2bf(fmaxf(glb[j] - fb, 0.f));
        }
        asm volatile("s_waitcnt lgkmcnt(0)" ::: "memory");
        bf16x8 a20 = *(const bf16x8*)&a2_bf[m*72 + g*8];
        bf16x8 a21 = *(const bf16x8*)&a2_bf[m*72 + 32 + g*8];
        #pragma unroll
        for (int no = 0; no < 4; ++no) {
            f32x4 acc = {0.f,0.f,0.f,0.f};
            acc = __builtin_amdgcn_mfma_f32_16x16x32_bf16(a20, bgw[no][0], acc, 0,0,0);
            acc = __builtin_amdgcn_mfma_f32_16x16x32_bf16(a21, bgw[no][1], acc, 0,0,0);
            #pragma unroll
            for (int j = 0; j < 4; ++j) {
                long long pr = p0 + g*4 + j;
                if (pr < N)
                    out[pr*64 + no*16 + m] = xv[no][j] + acc[j] + bgb[no];
            }
        }
        t = tn;
    }
}

extern "C" void kernel_launch(void* const* d_in, const int* in_sizes, int n_in,
                              void* d_out, int out_size, void* d_ws, size_t ws_size,
                              hipStream_t stream) {
    const float* x   = (const float*)d_in[0];
    const float* Wg1 = (const float*)d_in[1];
    const float* bg1 = (const float*)d_in[2];
    const float* Wg2 = (const float*)d_in[3];
    const float* bg2 = (const float*)d_in[4];
    const float* Wr1 = (const float*)d_in[5];
    const float* br1 = (const float*)d_in[6];
    const float* Wr2 = (const float*)d_in[7];
    const float* br2 = (const float*)d_in[8];
    const float* Wq1 = (const float*)d_in[9];
    const float* bq1 = (const float*)d_in[10];
    const float* Wq2 = (const float*)d_in[11];
    const float* bq2 = (const float*)d_in[12];
    const float* Wq3 = (const float*)d_in[13];
    const float* bq3 = (const float*)d_in[14];
    const int* nbr   = (const int*)d_in[15];
    const int* bid   = (const int*)d_in[16];
    const int* bsz   = (const int*)d_in[17];

    const long long N = (long long)in_sizes[0] / 64;

    float* cv   = (float*)d_ws;
    float* gl   = cv  + N * 32;
    float* r1   = gl  + N * 32;
    float* s12  = r1  + N * 32;
    float* m1   = s12 + N * 32;
    float* bsum = m1  + N;               // 128 floats used
    u16*   wsB  = (u16*)(bsum + 128);    // 216*512 u16 B-fragments

    float* out = (float*)d_out;

    hipMemsetAsync(bsum, 0, 128 * sizeof(float), stream);

    k0_prep<<<54, 256, 0, stream>>>(Wq1, Wq2, Wr1, Wr2, wsB);

    long long tiles = (N + 15) / 16;
    long long gwaves = (tiles + 3) / 4;
    int gblocks = (int)((gwaves + 3) / 4);
    k1_mfma<<<gblocks, 256, 0, stream>>>(x, Wg1, bg1, cv, gl, N);

    k2_mfma<<<768, 256, 0, stream>>>(cv, gl, nbr, bid, wsB, br1, bq1, bq2,
                                     r1, s12, m1, bsum, N);
    k3_mfma<<<768, 256, 0, stream>>>(r1, cv, gl, s12, m1, bsum, nbr, bid, wsB, br2,
                                     Wq3, bq3, Wg2, bg2, x, out, N, bsz);
}

// Round 22
// 212.685 us; speedup vs baseline: 1.0980x; 1.0980x over previous
//
#include <hip/hip_runtime.h>
#include <stdint.h>

typedef unsigned int u32;
typedef unsigned short u16;
typedef unsigned long long u64;
typedef __attribute__((ext_vector_type(8))) short bf16x8;
typedef __attribute__((ext_vector_type(4))) float f32x4;

#define HC 32

__device__ __forceinline__ float u2f(u32 u){ union{u32 i;float f;}v; v.i=u; return v.f; }
__device__ __forceinline__ u16 f2bf(float f){ union{float f;u32 i;}v; v.f=f; u32 i=v.i;
    return (u16)((i + 0x7FFFu + ((i>>16)&1u))>>16); }  // RNE
__device__ __forceinline__ short bfs(float f){ return (short)f2bf(f); }
__device__ __forceinline__ u32 packbf(float a, float b){ return (u32)f2bf(a) | ((u32)f2bf(b)<<16); }

// ---- K0: B-fragments for 4 conv matrices (slot = mat*54 + k*2 + oh) ----
__global__ __launch_bounds__(256) void k0_prep(
    const float* __restrict__ Wq1, const float* __restrict__ Wq2,
    const float* __restrict__ Wr1, const float* __restrict__ Wr2,
    u16* __restrict__ wsB)
{
    int it = blockIdx.x*256 + threadIdx.x;
    if (it >= 216*64) return;
    int l = it & 63, slot = it >> 6;
    int oh = slot & 1, k = (slot >> 1) % 27, mat = slot / 54;
    const float* W = (mat==0)?Wq1:(mat==1)?Wq2:(mat==2)?Wr1:Wr2;
    const float* src = W + k*1024 + oh*16 + (l & 15);
    int crow = (l >> 4) * 8;
    u32 w4[4];
    #pragma unroll
    for (int jj = 0; jj < 4; ++jj)
        w4[jj] = packbf(src[(crow + 2*jj)*32], src[(crow + 2*jj + 1)*32]);
    *(uint4*)&wsB[slot*512 + l*8] = make_uint4(w4[0], w4[1], w4[2], w4[3]);
}

// ---- K1: y = x @ Wg1 + bg1 -> cv | gl  (MFMA) ----
__global__ __launch_bounds__(256) void k1_mfma(
    const float* __restrict__ x, const float* __restrict__ Wg1, const float* __restrict__ bg1,
    float* __restrict__ cv, float* __restrict__ gl, long long N)
{
    const int lane = threadIdx.x & 63;
    const int m = lane & 15, g = lane >> 4;
    bf16x8 bw[4][2];
    #pragma unroll
    for (int no = 0; no < 4; ++no)
      #pragma unroll
      for (int kf = 0; kf < 2; ++kf)
        #pragma unroll
        for (int j = 0; j < 8; ++j)
            bw[no][kf][j] = bfs(Wg1[(kf*32 + g*8 + j)*64 + no*16 + m]);
    float bias4[4];
    #pragma unroll
    for (int no = 0; no < 4; ++no) bias4[no] = bg1[no*16 + m];

    const long long wave = (long long)blockIdx.x*4 + (threadIdx.x>>6);
    long long t0 = wave * 4;
    #pragma unroll 1
    for (long long t = t0; t < t0+4; ++t) {
        long long p0 = t*16;
        if (p0 >= N) break;
        long long pr_a = p0 + m; if (pr_a > N-1) pr_a = N-1;
        const float4* xr = (const float4*)(x + pr_a*64);
        bf16x8 aw[2];
        #pragma unroll
        for (int kf = 0; kf < 2; ++kf) {
            float4 lo = xr[kf*8 + g*2];
            float4 hi = xr[kf*8 + g*2 + 1];
            aw[kf][0]=bfs(lo.x); aw[kf][1]=bfs(lo.y); aw[kf][2]=bfs(lo.z); aw[kf][3]=bfs(lo.w);
            aw[kf][4]=bfs(hi.x); aw[kf][5]=bfs(hi.y); aw[kf][6]=bfs(hi.z); aw[kf][7]=bfs(hi.w);
        }
        #pragma unroll
        for (int no = 0; no < 4; ++no) {
            f32x4 acc = {0.f,0.f,0.f,0.f};
            acc = __builtin_amdgcn_mfma_f32_16x16x32_bf16(aw[0], bw[no][0], acc, 0,0,0);
            acc = __builtin_amdgcn_mfma_f32_16x16x32_bf16(aw[1], bw[no][1], acc, 0,0,0);
            #pragma unroll
            for (int j = 0; j < 4; ++j) {
                long long pr = p0 + g*4 + j;
                if (pr < N) {
                    float v = acc[j] + bias4[no];
                    if (no < 2) cv[pr*32 + no*16 + m] = v;
                    else        gl[pr*32 + (no-2)*16 + m] = v;
                }
            }
        }
    }
}

// ---- tile machinery ----
__device__ __forceinline__ void load_nbr(
    const int* __restrict__ nbr, long long N, long long p0, int lane, int* nbrv)
{
    #pragma unroll
    for (int ch = 0; ch < 7; ++ch) {
        int i = ch*64 + lane;
        int kk = i >> 4, pp = i & 15;
        nbrv[ch] = (i < 432 && p0 + pp < N) ? nbr[(long long)kk*N + p0 + pp] : -1;
    }
}

// ballot/compact only — nbr values come from pre-loaded registers
__device__ __forceinline__ void enum_tile_reg(
    const int* nbrv,
    u16* plist, int* ilist, u16* slist, u16* sstart,
    int lane, u32& np_out, u32& ns_out)
{
    u32 np = 0, ns = 0;
    #pragma unroll
    for (int ch = 0; ch < 7; ++ch) {
        int i = ch*64 + lane;
        int kk = i >> 4, pp = i & 15;
        int ixv = nbrv[ch];
        u64 b = __ballot(ixv >= 0);
        u32 kact = 0;
        #pragma unroll
        for (int q2 = 0; q2 < 4; ++q2)
            kact |= ((((b >> (16*q2)) & 0xffffull) != 0ull) ? 1u : 0u) << q2;
        if (ixv >= 0) {
            u64 ltm = (1ull << lane) - 1ull;
            u32 pos = np + (u32)__popcll(b & ltm);
            int q2 = lane >> 4;
            u32 s = ns + __popc(kact & ((1u << q2) - 1u));
            if (pos < 224) {
                plist[pos] = (u16)((s << 9) | (u32)pp);
                ilist[pos] = ixv;
                u64 subm = 0xffffull << (16*q2);
                if ((b & subm & ltm) == 0ull) { slist[s] = (u16)kk; sstart[s] = (u16)pos; }
            }
        }
        np += (u32)__popcll(b);
        ns += __popc(kact);
    }
    if (np > 224) np = 224;
    np_out = np; ns_out = ns;
}

template<int KAv>
__device__ __forceinline__ void gather_batch(
    const float* __restrict__ src, u16* A,
    const u16* plist, const int* ilist,
    u32 jS, u32 jE, u32 base, int c32, int hf)
{
    constexpr int STR = KAv*32 + 8;
    constexpr int U4R = KAv*4;
    constexpr int NU4 = 16*U4R;
    const int lane = threadIdx.x & 63;
    uint4 z4 = make_uint4(0u,0u,0u,0u);
    #pragma unroll
    for (int w = 0; w < NU4/64; ++w) {
        int q = w*64 + lane;
        int r = q / U4R, c8 = q - r*U4R;
        *(uint4*)&A[r*STR + c8*8] = z4;
    }
    asm volatile("s_waitcnt lgkmcnt(0)" ::: "memory");
    for (u32 j0 = jS; j0 < jE; j0 += 16) {
        float v[8]; u32 mt[8];
        #pragma unroll
        for (int tt = 0; tt < 8; ++tt) {
            u32 pj = j0 + 2*tt + (u32)hf;
            bool val = pj < jE;
            u32 pm = val ? (u32)plist[pj] : 0u;
            int ix = val ? ilist[pj] : 0;
            mt[tt] = val ? (pm | 0x80000000u) : 0u;
            v[tt] = val ? src[(long long)ix*32 + c32] : 0.f;
        }
        #pragma unroll
        for (int tt = 0; tt < 8; ++tt) {
            if (mt[tt] >> 31) {
                u32 sl = ((mt[tt] >> 9) & 31u) - base;
                u32 p = mt[tt] & 15u;
                A[p*STR + sl*32 + c32] = f2bf(v[tt]);
            }
        }
    }
    asm volatile("s_waitcnt lgkmcnt(0)" ::: "memory");
}

template<int KAv>
__device__ __forceinline__ void gather_batch2(
    const float* __restrict__ src0, const float* __restrict__ src1,
    u16* A0, u16* A1,
    const u16* plist, const int* ilist,
    u32 jS, u32 jE, u32 base, int c32, int hf)
{
    constexpr int STR = KAv*32 + 8;
    constexpr int U4R = KAv*4;
    constexpr int NU4 = 16*U4R;
    const int lane = threadIdx.x & 63;
    uint4 z4 = make_uint4(0u,0u,0u,0u);
    #pragma unroll
    for (int w = 0; w < NU4/64; ++w) {
        int q = w*64 + lane;
        int r = q / U4R, c8 = q - r*U4R;
        *(uint4*)&A0[r*STR + c8*8] = z4;
        *(uint4*)&A1[r*STR + c8*8] = z4;
    }
    asm volatile("s_waitcnt lgkmcnt(0)" ::: "memory");
    for (u32 j0 = jS; j0 < jE; j0 += 16) {
        float v0[8], v1[8]; u32 mt[8];
        #pragma unroll
        for (int tt = 0; tt < 8; ++tt) {
            u32 pj = j0 + 2*tt + (u32)hf;
            bool val = pj < jE;
            u32 pm = val ? (u32)plist[pj] : 0u;
            int ix = val ? ilist[pj] : 0;
            mt[tt] = val ? (pm | 0x80000000u) : 0u;
            v0[tt] = val ? src0[(long long)ix*32 + c32] : 0.f;
            v1[tt] = val ? src1[(long long)ix*32 + c32] : 0.f;
        }
        #pragma unroll
        for (int tt = 0; tt < 8; ++tt) {
            if (mt[tt] >> 31) {
                u32 sl = ((mt[tt] >> 9) & 31u) - base;
                u32 p = mt[tt] & 15u;
                A0[p*STR + sl*32 + c32] = f2bf(v0[tt]);
                A1[p*STR + sl*32 + c32] = f2bf(v1[tt]);
            }
        }
    }
    asm volatile("s_waitcnt lgkmcnt(0)" ::: "memory");
}

// ---- K2 fused: r1 + s12/m1/bsum in one MFMA-tile pass (KA=5, nbr pipelined) ----
#define KA2 5
#define STR2 (KA2*32 + 8)
__global__ __launch_bounds__(256, 1) void k2_mfma(
    const float* __restrict__ cv, const float* __restrict__ gl,
    const int* __restrict__ nbr, const int* __restrict__ batch_id,
    const u16* __restrict__ wsB,
    const float* __restrict__ br1, const float* __restrict__ bq1,
    const float* __restrict__ bq2,
    float* __restrict__ r1, float* __restrict__ s12, float* __restrict__ m1,
    float* __restrict__ bsum, long long N)
{
    __shared__ __align__(16) u16 Acv[4][16*STR2];
    __shared__ __align__(16) u16 Agl[4][16*STR2];
    __shared__ u16 plist_s[4][224];
    __shared__ int ilist_s[4][224];
    __shared__ u16 slist_s[4][32];
    __shared__ u16 sstart_s[4][32];
    __shared__ float lbs[128];

    if (threadIdx.x < 128) lbs[threadIdx.x] = 0.f;
    __syncthreads();

    const int wid = threadIdx.x >> 6;
    const int lane = threadIdx.x & 63;
    const int m = lane & 15, g = lane >> 4;
    const int c32 = lane & 31, hf = lane >> 5;
    u16* A0 = Acv[wid];
    u16* A1 = Agl[wid];
    u16* plist = plist_s[wid];
    int* ilist = ilist_s[wid];
    u16* slist = slist_s[wid];
    u16* sstart = sstart_s[wid];

    const float bra = br1[m], brb = br1[16+m];
    const float b1a = bq1[m], b1b = bq1[16+m], b2a = bq2[m], b2b = bq2[16+m];

    const long long ntiles = (N + 15) >> 4;
    const long long tstride = (long long)gridDim.x*4;
    long long t = (long long)blockIdx.x*4 + wid;
    int nbrv[7];
    if (t < ntiles) load_nbr(nbr, N, t*16, lane, nbrv);
    for (; t < ntiles; ) {
        const long long p0 = t*16;
        u32 np, ns;
        enum_tile_reg(nbrv, plist, ilist, slist, sstart, lane, np, ns);
        // prefetch next tile's nbr (flies under gather+MFMA) and this tile's batch_id
        long long tn = t + tstride;
        if (tn < ntiles) load_nbr(nbr, N, tn*16, lane, nbrv);
        int bb[4];
        #pragma unroll
        for (int j = 0; j < 4; ++j) {
            long long pr = p0 + g*4 + j; if (pr > N-1) pr = N-1;
            bb[j] = batch_id[pr];
        }

        f32x4 accr0 = {0.f,0.f,0.f,0.f}, accr1 = {0.f,0.f,0.f,0.f};
        f32x4 acc10 = {0.f,0.f,0.f,0.f}, acc11 = {0.f,0.f,0.f,0.f};
        f32x4 acc20 = {0.f,0.f,0.f,0.f}, acc21 = {0.f,0.f,0.f,0.f};
        asm volatile("s_waitcnt lgkmcnt(0)" ::: "memory");
        for (u32 base = 0; base < ns; base += KA2) {
            u32 sEnd = base + KA2; if (sEnd > ns) sEnd = ns;
            u32 jS = sstart[base];
            u32 jE = (sEnd < ns) ? (u32)sstart[sEnd] : np;
            gather_batch2<KA2>(cv, gl, A0, A1, plist, ilist, jS, jE, base, c32, hf);
            for (u32 s = base; s < sEnd; ++s) {
                int sl = (int)(s - base);
                int k = slist[s];
                bf16x8 afc = *(const bf16x8*)&A0[m*STR2 + sl*32 + g*8];
                bf16x8 afg = *(const bf16x8*)&A1[m*STR2 + sl*32 + g*8];
                bf16x8 wr0 = *(const bf16x8*)&wsB[(108 + k*2 + 0)*512 + lane*8];
                bf16x8 wr1 = *(const bf16x8*)&wsB[(108 + k*2 + 1)*512 + lane*8];
                bf16x8 w10 = *(const bf16x8*)&wsB[(k*2 + 0)*512 + lane*8];
                bf16x8 w11 = *(const bf16x8*)&wsB[(k*2 + 1)*512 + lane*8];
                bf16x8 w20 = *(const bf16x8*)&wsB[(54 + k*2 + 0)*512 + lane*8];
                bf16x8 w21 = *(const bf16x8*)&wsB[(54 + k*2 + 1)*512 + lane*8];
                accr0 = __builtin_amdgcn_mfma_f32_16x16x32_bf16(afc, wr0, accr0, 0,0,0);
                accr1 = __builtin_amdgcn_mfma_f32_16x16x32_bf16(afc, wr1, accr1, 0,0,0);
                acc10 = __builtin_amdgcn_mfma_f32_16x16x32_bf16(afg, w10, acc10, 0,0,0);
                acc11 = __builtin_amdgcn_mfma_f32_16x16x32_bf16(afg, w11, acc11, 0,0,0);
                acc20 = __builtin_amdgcn_mfma_f32_16x16x32_bf16(afg, w20, acc20, 0,0,0);
                acc21 = __builtin_amdgcn_mfma_f32_16x16x32_bf16(afg, w21, acc21, 0,0,0);
            }
        }
        #pragma unroll
        for (int j = 0; j < 4; ++j) {
            long long pr = p0 + g*4 + j;
            if (pr < N) {
                r1[pr*32 + m]      = fmaxf(accr0[j] + bra, 0.f);
                r1[pr*32 + 16 + m] = fmaxf(accr1[j] + brb, 0.f);
                float o1a = fmaxf(acc10[j] + b1a, 0.f);
                float o1b = fmaxf(acc11[j] + b1b, 0.f);
                float o2a = fmaxf(acc20[j] + b2a, 0.f);
                float o2b = fmaxf(acc21[j] + b2b, 0.f);
                s12[pr*32 + m]      = o1a + o2a;
                s12[pr*32 + 16 + m] = o1b + o2b;
                float rs = o1a + o1b;
                #pragma unroll
                for (int d = 1; d < 16; d <<= 1) rs += __shfl_xor(rs, d, 64);
                if (m == 0) m1[pr] = rs * (1.f/32.f);
                atomicAdd(&lbs[bb[j]*32 + m], o2a);
                atomicAdd(&lbs[bb[j]*32 + 16 + m], o2b);
            }
        }
        t = tn;
    }
    __syncthreads();
    if (threadIdx.x < 128) atomicAdd(&bsum[threadIdx.x], lbs[threadIdx.x]);
}

// ---- K3: r2-conv (KA=10) + epilogue prefetch + nbr pipeline -> out ----
#define KA3 10
#define STR3 (KA3*32 + 8)
__global__ __launch_bounds__(256, 1) void k3_mfma(
    const float* __restrict__ r1, const float* __restrict__ cv,
    const float* __restrict__ gl, const float* __restrict__ s12,
    const float* __restrict__ m1, const float* __restrict__ bsum,
    const int* __restrict__ nbr, const int* __restrict__ batch_id,
    const u16* __restrict__ wsB, const float* __restrict__ br2,
    const float* __restrict__ Wq3, const float* __restrict__ bq3,
    const float* __restrict__ Wg2, const float* __restrict__ bg2,
    const float* __restrict__ x, float* __restrict__ out,
    long long N, const int* __restrict__ bsz)
{
    __shared__ __align__(16) u16 Acmp[4][16*STR3];
    __shared__ u16 plist_s[4][224];
    __shared__ int ilist_s[4][224];
    __shared__ u16 slist_s[4][32];
    __shared__ u16 sstart_s[4][32];

    const int wid = threadIdx.x >> 6;
    const int lane = threadIdx.x & 63;
    const int m = lane & 15, g = lane >> 4;
    const int c32 = lane & 31, hf = lane >> 5;
    u16* A = Acmp[wid];
    u16* plist = plist_s[wid];
    int* ilist = ilist_s[wid];
    u16* slist = slist_s[wid];
    u16* sstart = sstart_s[wid];
    u16* fin_bf = A;          // aliased into A (dead after conv)
    u16* a2_bf  = A + 640;

    bf16x8 bq[2];
    #pragma unroll
    for (int no = 0; no < 2; ++no)
      #pragma unroll
      for (int j = 0; j < 8; ++j)
        bq[no][j] = bfs(Wq3[(g*8+j)*32 + no*16 + m]);
    bf16x8 bgw[4][2];
    #pragma unroll
    for (int no = 0; no < 4; ++no)
      #pragma unroll
      for (int kf = 0; kf < 2; ++kf)
        #pragma unroll
        for (int j = 0; j < 8; ++j)
          bgw[no][kf][j] = bfs(Wg2[(kf*32 + g*8 + j)*64 + no*16 + m]);
    const float br2a = br2[m], br2b = br2[16+m];
    const float bq3a = bq3[m], bq3b = bq3[16+m];
    float bgb[4];
    #pragma unroll
    for (int no = 0; no < 4; ++no) bgb[no] = bg2[no*16 + m];
    const float invNP = (float)(*bsz) / (float)N;
    const int p_lin = lane >> 2, c0 = (lane & 3) * 8;

    const long long ntiles = (N + 15) >> 4;
    const long long tstride = (long long)gridDim.x*4;
    long long t = (long long)blockIdx.x*4 + wid;
    int nbrv[7];
    if (t < ntiles) load_nbr(nbr, N, t*16, lane, nbrv);
    for (; t < ntiles; ) {
        const long long p0 = t*16;
        u32 np, ns;
        enum_tile_reg(nbrv, plist, ilist, slist, sstart, lane, np, ns);
        long long tn = t + tstride;
        if (tn < ntiles) load_nbr(nbr, N, tn*16, lane, nbrv);

        // ---- PREFETCH epilogue operands ----
        float cva[4], cvb[4], gla[4], glb[4], xv[4][4];
        #pragma unroll
        for (int j = 0; j < 4; ++j) {
            int row = g*4 + j;
            long long pr = p0 + row; if (pr > N-1) pr = N-1;
            cva[j] = cv[pr*32 + m];      cvb[j] = cv[pr*32 + 16 + m];
            gla[j] = gl[pr*32 + m];      glb[j] = gl[pr*32 + 16 + m];
            #pragma unroll
            for (int no = 0; no < 4; ++no) xv[no][j] = x[pr*64 + no*16 + m];
        }
        float m1v; float bsv[8], sv[8];
        {
            long long pp = p0 + p_lin; if (pp > N-1) pp = N-1;
            m1v = m1[pp];
            int b = batch_id[pp];
            const float4* bsp = (const float4*)(bsum + b*32 + c0);
            float4 bs0 = bsp[0], bs1 = bsp[1];
            const float4* s12p = (const float4*)(s12 + pp*32 + c0);
            float4 s0 = s12p[0], s1 = s12p[1];
            bsv[0]=bs0.x; bsv[1]=bs0.y; bsv[2]=bs0.z; bsv[3]=bs0.w;
            bsv[4]=bs1.x; bsv[5]=bs1.y; bsv[6]=bs1.z; bsv[7]=bs1.w;
            sv[0]=s0.x; sv[1]=s0.y; sv[2]=s0.z; sv[3]=s0.w;
            sv[4]=s1.x; sv[5]=s1.y; sv[6]=s1.z; sv[7]=s1.w;
        }

        // ---- conv phase ----
        f32x4 acc0 = {0.f,0.f,0.f,0.f}, acc1 = {0.f,0.f,0.f,0.f};
        asm volatile("s_waitcnt lgkmcnt(0)" ::: "memory");
        for (u32 base = 0; base < ns; base += KA3) {
            u32 sEnd = base + KA3; if (sEnd > ns) sEnd = ns;
            u32 jS = sstart[base];
            u32 jE = (sEnd < ns) ? (u32)sstart[sEnd] : np;
            gather_batch<KA3>(r1, A, plist, ilist, jS, jE, base, c32, hf);
            for (u32 s = base; s < sEnd; ++s) {
                int sl = (int)(s - base);
                int k = slist[s];
                bf16x8 af = *(const bf16x8*)&A[m*STR3 + sl*32 + g*8];
                bf16x8 w0 = *(const bf16x8*)&wsB[(162 + k*2 + 0)*512 + lane*8];
                bf16x8 w1 = *(const bf16x8*)&wsB[(162 + k*2 + 1)*512 + lane*8];
                acc0 = __builtin_amdgcn_mfma_f32_16x16x32_bf16(af, w0, acc0, 0,0,0);
                acc1 = __builtin_amdgcn_mfma_f32_16x16x32_bf16(af, w1, acc1, 0,0,0);
            }
        }
        asm volatile("s_waitcnt lgkmcnt(0)" ::: "memory");
        // cx2 -> a2 tile
        #pragma unroll
        for (int j = 0; j < 4; ++j) {
            int row = g*4 + j;
            a2_bf[row*72 + m]      = f2bf(fmaxf(acc0[j] + br2a, 0.f) + 2.f*cva[j]);
            a2_bf[row*72 + 16 + m] = f2bf(fmaxf(acc1[j] + br2b, 0.f) + 2.f*cvb[j]);
        }
        {
            bf16x8 fbv;
            #pragma unroll
            for (int j = 0; j < 8; ++j) {
                float enc = sqrtf(m1v * bsv[j] * invNP + 1e-12f);
                fbv[j] = bfs(enc + sv[j]);
            }
            *(bf16x8*)&fin_bf[p_lin*40 + c0] = fbv;
        }
        asm volatile("s_waitcnt lgkmcnt(0)" ::: "memory");
        bf16x8 af2 = *(const bf16x8*)&fin_bf[m*40 + g*8];
        f32x4 f0 = {0.f,0.f,0.f,0.f}, f1 = {0.f,0.f,0.f,0.f};
        f0 = __builtin_amdgcn_mfma_f32_16x16x32_bf16(af2, bq[0], f0, 0,0,0);
        f1 = __builtin_amdgcn_mfma_f32_16x16x32_bf16(af2, bq[1], f1, 0,0,0);
        #pragma unroll
        for (int j = 0; j < 4; ++j) {
            int row = g*4 + j;
            float fa = fmaxf(f0[j] + bq3a, 0.f);
            float fb = fmaxf(f1[j] + bq3b, 0.f);
            a2_bf[row*72 + 32 + m] = f2bf(fmaxf(gla[j] - fa, 0.f));
            a2_bf[row*72 + 48 + m] = f2bf(fmaxf(glb[j] - fb, 0.f));
        }
        asm volatile("s_waitcnt lgkmcnt(0)" ::: "memory");
        bf16x8 a20 = *(const bf16x8*)&a2_bf[m*72 + g*8];
        bf16x8 a21 = *(const bf16x8*)&a2_bf[m*72 + 32 + g*8];
        #pragma unroll
        for (int no = 0; no < 4; ++no) {
            f32x4 acc = {0.f,0.f,0.f,0.f};
            acc = __builtin_amdgcn_mfma_f32_16x16x32_bf16(a20, bgw[no][0], acc, 0,0,0);
            acc = __builtin_amdgcn_mfma_f32_16x16x32_bf16(a21, bgw[no][1], acc, 0,0,0);
            #pragma unroll
            for (int j = 0; j < 4; ++j) {
                long long pr = p0 + g*4 + j;
                if (pr < N)
                    out[pr*64 + no*16 + m] = xv[no][j] + acc[j] + bgb[no];
            }
        }
        t = tn;
    }
}

extern "C" void kernel_launch(void* const* d_in, const int* in_sizes, int n_in,
                              void* d_out, int out_size, void* d_ws, size_t ws_size,
                              hipStream_t stream) {
    const float* x   = (const float*)d_in[0];
    const float* Wg1 = (const float*)d_in[1];
    const float* bg1 = (const float*)d_in[2];
    const float* Wg2 = (const float*)d_in[3];
    const float* bg2 = (const float*)d_in[4];
    const float* Wr1 = (const float*)d_in[5];
    const float* br1 = (const float*)d_in[6];
    const float* Wr2 = (const float*)d_in[7];
    const float* br2 = (const float*)d_in[8];
    const float* Wq1 = (const float*)d_in[9];
    const float* bq1 = (const float*)d_in[10];
    const float* Wq2 = (const float*)d_in[11];
    const float* bq2 = (const float*)d_in[12];
    const float* Wq3 = (const float*)d_in[13];
    const float* bq3 = (const float*)d_in[14];
    const int* nbr   = (const int*)d_in[15];
    const int* bid   = (const int*)d_in[16];
    const int* bsz   = (const int*)d_in[17];

    const long long N = (long long)in_sizes[0] / 64;

    float* cv   = (float*)d_ws;
    float* gl   = cv  + N * 32;
    float* r1   = gl  + N * 32;
    float* s12  = r1  + N * 32;
    float* m1   = s12 + N * 32;
    float* bsum = m1  + N;               // 128 floats used
    u16*   wsB  = (u16*)(bsum + 128);    // 216*512 u16 B-fragments

    float* out = (float*)d_out;

    hipMemsetAsync(bsum, 0, 128 * sizeof(float), stream);

    k0_prep<<<54, 256, 0, stream>>>(Wq1, Wq2, Wr1, Wr2, wsB);

    long long tiles = (N + 15) / 16;
    long long gwaves = (tiles + 3) / 4;
    int gblocks = (int)((gwaves + 3) / 4);
    k1_mfma<<<gblocks, 256, 0, stream>>>(x, Wg1, bg1, cv, gl, N);

    k2_mfma<<<768, 256, 0, stream>>>(cv, gl, nbr, bid, wsB, br1, bq1, bq2,
                                     r1, s12, m1, bsum, N);
    k3_mfma<<<768, 256, 0, stream>>>(r1, cv, gl, s12, m1, bsum, nbr, bid, wsB, br2,
                                     Wq3, bq3, Wg2, bg2, x, out, N, bsz);
}